// Round 11
// baseline (375.382 us; speedup 1.0000x reference)
//
#include <hip/hip_runtime.h>
#include <math.h>

#define NF 128
#define FH 512
#define SQRT_DH 5.656854249492380f
#define LN_EPS 1e-5f

typedef __attribute__((ext_vector_type(8))) short short8;
typedef __attribute__((ext_vector_type(4))) float f32x4;

__device__ __forceinline__ unsigned short f2bf(float x) {
    union { float f; unsigned u; } c; c.f = x;
    unsigned u = c.u;
    return (unsigned short)((u + 0x7fffu + ((u >> 16) & 1u)) >> 16);
}
__device__ __forceinline__ float bf2f(unsigned short h) {
    union { unsigned u; float f; } c; c.u = (unsigned)h << 16; return c.f;
}
__device__ __forceinline__ float lo_bf(unsigned u) {
    union { unsigned u; float f; } c; c.u = u << 16; return c.f;
}
__device__ __forceinline__ float hi_bf(unsigned u) {
    union { unsigned u; float f; } c; c.u = u & 0xffff0000u; return c.f;
}

// ---------------- weight prep ------------------------------------------------
// B-fragment order: frag[kt][nt][lane][i] = W[kt*32 + (lane>>4)*8 + i][nt*16 + (lane&15)]
__global__ __launch_bounds__(256) void prep_w(
    const float* __restrict__ W1, const float* __restrict__ W2,
    const float* __restrict__ Wq, const float* __restrict__ Wk,
    unsigned short* __restrict__ W1f, unsigned short* __restrict__ W2f,
    unsigned short* __restrict__ Wqhi, unsigned short* __restrict__ Wqlo,
    unsigned short* __restrict__ Wkhi, unsigned short* __restrict__ Wklo)
{
    int f = blockIdx.x * 256 + threadIdx.x;   // 0..65535
    int i = f & 7, l = (f >> 3) & 63;
    int lg = l >> 4, l15 = l & 15;
    {
        int ntg = (f >> 9) & 31, kt = f >> 14;
        int k = kt * 32 + lg * 8 + i, n = ntg * 16 + l15;
        W1f[f] = f2bf(W1[k * FH + n]);
    }
    {
        int nt2 = (f >> 9) & 7, kt2 = f >> 12;
        int k = kt2 * 32 + lg * 8 + i, n = nt2 * 16 + l15;
        W2f[f] = f2bf(W2[k * NF + n]);
    }
    if (f < 16384) {
        int nt = (f >> 9) & 7, kt = f >> 12;
        int k = kt * 32 + lg * 8 + i, n = nt * 16 + l15;
        float vq = Wq[k * NF + n];
        unsigned short qh = f2bf(vq);
        Wqhi[f] = qh; Wqlo[f] = f2bf(vq - bf2f(qh));
        float vk = Wk[k * NF + n];
        unsigned short kh = f2bf(vk);
        Wkhi[f] = kh; Wklo[f] = f2bf(vk - bf2f(kh));
    }
}

// ---------------- Kernel 1: q/k projections via MFMA (hi/lo split) ----------
__global__ __launch_bounds__(256) void qk_mfma(
    const float* __restrict__ feat,
    const unsigned short* __restrict__ Wqhi, const unsigned short* __restrict__ Wqlo,
    const unsigned short* __restrict__ Wkhi, const unsigned short* __restrict__ Wklo,
    unsigned* __restrict__ kq, int N)
{
    const int tid = threadIdx.x;
    const int l = tid & 63, wid = tid >> 6;
    const int l15 = l & 15, lg = l >> 4;
    const int n0 = blockIdx.x * 32;

    f32x4 accq[2][2], acck[2][2];
    #pragma unroll
    for (int mf = 0; mf < 2; ++mf)
        #pragma unroll
        for (int nt = 0; nt < 2; ++nt) {
            accq[mf][nt] = (f32x4){0.f, 0.f, 0.f, 0.f};
            acck[mf][nt] = (f32x4){0.f, 0.f, 0.f, 0.f};
        }

    #pragma unroll
    for (int kt = 0; kt < 4; ++kt) {
        short8 ahi[2], alo[2];
        #pragma unroll
        for (int mf = 0; mf < 2; ++mf) {
            int n = n0 + mf * 16 + l15;
            float v[8];
            if (n < N) {
                const float4* p = (const float4*)(feat + (size_t)n * NF + kt * 32 + lg * 8);
                float4 v0 = p[0], v1 = p[1];
                v[0] = v0.x; v[1] = v0.y; v[2] = v0.z; v[3] = v0.w;
                v[4] = v1.x; v[5] = v1.y; v[6] = v1.z; v[7] = v1.w;
            } else {
                #pragma unroll
                for (int i = 0; i < 8; ++i) v[i] = 0.f;
            }
            #pragma unroll
            for (int i = 0; i < 8; ++i) {
                unsigned short h = f2bf(v[i]);
                ahi[mf][i] = (short)h;
                alo[mf][i] = (short)f2bf(v[i] - bf2f(h));
            }
        }
        #pragma unroll
        for (int nt = 0; nt < 2; ++nt) {
            int ntg = wid * 2 + nt;
            size_t fo = ((size_t)(kt * 8 + ntg) * 64 + l) * 8;
            short8 bqh = *(const short8*)(Wqhi + fo);
            short8 bql = *(const short8*)(Wqlo + fo);
            short8 bkh = *(const short8*)(Wkhi + fo);
            short8 bkl = *(const short8*)(Wklo + fo);
            #pragma unroll
            for (int mf = 0; mf < 2; ++mf) {
                accq[mf][nt] = __builtin_amdgcn_mfma_f32_16x16x32_bf16(ahi[mf], bqh, accq[mf][nt], 0, 0, 0);
                accq[mf][nt] = __builtin_amdgcn_mfma_f32_16x16x32_bf16(alo[mf], bqh, accq[mf][nt], 0, 0, 0);
                accq[mf][nt] = __builtin_amdgcn_mfma_f32_16x16x32_bf16(ahi[mf], bql, accq[mf][nt], 0, 0, 0);
                acck[mf][nt] = __builtin_amdgcn_mfma_f32_16x16x32_bf16(ahi[mf], bkh, acck[mf][nt], 0, 0, 0);
                acck[mf][nt] = __builtin_amdgcn_mfma_f32_16x16x32_bf16(alo[mf], bkh, acck[mf][nt], 0, 0, 0);
                acck[mf][nt] = __builtin_amdgcn_mfma_f32_16x16x32_bf16(ahi[mf], bkl, acck[mf][nt], 0, 0, 0);
            }
        }
    }

    #pragma unroll
    for (int mf = 0; mf < 2; ++mf) {
        #pragma unroll
        for (int nt = 0; nt < 2; ++nt) {
            int colg = wid * 32 + nt * 16 + l15;
            #pragma unroll
            for (int r = 0; r < 4; ++r) {
                int n = n0 + mf * 16 + lg * 4 + r;
                if (n < N) {
                    float kk = acck[mf][nt][r];
                    float qq = accq[mf][nt][r];
                    float e = __expf(SQRT_DH * kk);
                    kq[(size_t)n * NF + colg] =
                        ((unsigned)f2bf(qq * e) << 16) | (unsigned)f2bf(e);
                }
            }
        }
    }
}

// ---------------- CSR build ------------------------------------------------
__global__ __launch_bounds__(256) void hist_kernel(
    const int* __restrict__ dst, int* __restrict__ deg, int E)
{
    int i = blockIdx.x * 256 + threadIdx.x;
    if (i < E) atomicAdd(&deg[dst[i]], 1);
}

__global__ __launch_bounds__(1024) void scan_blk(
    const int* __restrict__ deg, int* __restrict__ off,
    int* __restrict__ bsum, int N)
{
    __shared__ int ws[16];
    const int tid = threadIdx.x, lane = tid & 63, w = tid >> 6;
    int i = blockIdx.x * 1024 + tid;
    int v = (i < N) ? deg[i] : 0;
    int x = v;
    #pragma unroll
    for (int o = 1; o < 64; o <<= 1) {
        int t = __shfl_up(x, o);
        if (lane >= o) x += t;
    }
    if (lane == 63) ws[w] = x;
    __syncthreads();
    if (w == 0 && lane < 16) {
        int s = ws[lane];
        #pragma unroll
        for (int o = 1; o < 16; o <<= 1) {
            int t = __shfl_up(s, o);
            if (lane >= o) s += t;
        }
        ws[lane] = s;
    }
    __syncthreads();
    int wbase = (w == 0) ? 0 : ws[w - 1];
    int incl = wbase + x;
    if (i < N) off[i] = incl - v;
    if (tid == 1023) bsum[blockIdx.x] = incl;
}

__global__ __launch_bounds__(64) void scan_mid(int* __restrict__ bsum, int nb)
{
    int lane = threadIdx.x;
    int v = (lane < nb) ? bsum[lane] : 0;
    int x = v;
    #pragma unroll
    for (int o = 1; o < 64; o <<= 1) {
        int t = __shfl_up(x, o);
        if (lane >= o) x += t;
    }
    if (lane < nb) bsum[lane] = x - v;
}

__global__ __launch_bounds__(1024) void scan_add(
    int* __restrict__ off, int* __restrict__ cursor,
    const int* __restrict__ bsum, int N, int E)
{
    int i = blockIdx.x * 1024 + threadIdx.x;
    if (i < N) {
        int o = off[i] + bsum[blockIdx.x];
        off[i] = o; cursor[i] = o;
    }
    if (i == 0) off[N] = E;
}

__global__ __launch_bounds__(256) void scatter_kernel(
    const int* __restrict__ src, const int* __restrict__ dst,
    int* __restrict__ cursor, int* __restrict__ col, int E)
{
    int i = blockIdx.x * 256 + threadIdx.x;
    if (i < E) {
        int pos = atomicAdd(&cursor[dst[i]], 1);
        col[pos] = src[i];
    }
}

// canonicalize segment order: one wave per node, 64-lane bitonic via shfl_xor
__global__ __launch_bounds__(256) void sort_csr(
    const int* __restrict__ off, int* __restrict__ col, int N)
{
    const int wid  = threadIdx.x >> 6;
    const int lane = threadIdx.x & 63;
    const int n = blockIdx.x * 4 + wid;
    if (n >= N) return;
    const int e0 = off[n], e1 = off[n + 1];
    const int len = e1 - e0;
    if (len <= 1) return;
    if (len <= 64) {
        int v = (lane < len) ? col[e0 + lane] : 0x7fffffff;
        #pragma unroll
        for (int k = 2; k <= 64; k <<= 1) {
            #pragma unroll
            for (int j = k >> 1; j > 0; j >>= 1) {
                int other = __shfl_xor(v, j);
                bool keepMin = (((lane & j) == 0) == ((lane & k) == 0));
                v = keepMin ? (v < other ? v : other)
                            : (v > other ? v : other);
            }
        }
        if (lane < len) col[e0 + lane] = v;
    } else if (lane == 0) {
        for (int i = e0 + 1; i < e1; ++i) {
            int v = col[i];
            int j = i - 1;
            while (j >= e0 && col[j] > v) { col[j + 1] = col[j]; --j; }
            col[j + 1] = v;
        }
    }
}

// ---------------- fused gather + LN1 + FFN + LN2 ---------------------------
// Phase A: per-wave CSR gather (8 rows/wave, 2 ch/lane), in-wave LN1 ->
//   hx[32][128] bf16 in LDS (16B-block XOR swizzle: byte ^= (row&7)<<4).
// Phase B: GEMM1 (A from hx, B = W1f global) + PReLU -> hlds (swizzled).
// Phase C: GEMM2 (A from hlds, B = W2f global), residual from hx,
//   LN2 via 16-lane shfl partials -> sred -> finalize.  3 barriers.
__global__ __launch_bounds__(256) void gfn_fused(
    const float* __restrict__ feat, const unsigned* __restrict__ kq,
    const int* __restrict__ off, const int* __restrict__ col,
    const float* __restrict__ ln_g, const float* __restrict__ ln_b,
    const unsigned short* __restrict__ W1f, const unsigned short* __restrict__ W2f,
    const float* __restrict__ b1, const float* __restrict__ alpha,
    const float* __restrict__ b2, float* __restrict__ out, int N)
{
    __shared__ unsigned short hx[32 * 128];     // 8 KB, LN1 out (bf16, swizzled)
    __shared__ unsigned short hlds[32 * 512];   // 32 KB, h (bf16, swizzled)
    __shared__ float sredS[32][4];
    __shared__ float sredQ[32][4];

    const int tid = threadIdx.x;
    const int l = tid & 63;
    const int wid = tid >> 6;
    const int l15 = l & 15;
    const int lg = l >> 4;
    const int n0 = blockIdx.x * 32;

    char* hxb = (char*)hx;
    char* hbase = (char*)hlds;

    // ---- Phase A: gather + LN1, wave-independent
    {
        const float ga = ln_g[l], gb = ln_g[l + 64];
        const float ba = ln_b[l], bb = ln_b[l + 64];
        for (int m = 0; m < 8; ++m) {
            const int row = wid * 8 + m;
            const int n = n0 + row;
            float x0 = 0.f, x1 = 0.f;
            if (n < N) {
                const int e0 = off[n], e1 = off[n + 1];
                float da0 = 0.f, qa0 = 0.f, da1 = 0.f, qa1 = 0.f;
                float db0 = 0.f, qb0 = 0.f, db1 = 0.f, qb1 = 0.f;
                int e = e0;
                for (; e + 1 < e1; e += 2) {
                    const unsigned* r0 = kq + (size_t)col[e]     * NF;
                    const unsigned* r1 = kq + (size_t)col[e + 1] * NF;
                    unsigned ua0 = r0[l], ub0 = r0[l + 64];
                    unsigned ua1 = r1[l], ub1 = r1[l + 64];
                    da0 += lo_bf(ua0); qa0 += hi_bf(ua0);
                    db0 += lo_bf(ub0); qb0 += hi_bf(ub0);
                    da1 += lo_bf(ua1); qa1 += hi_bf(ua1);
                    db1 += lo_bf(ub1); qb1 += hi_bf(ub1);
                }
                if (e < e1) {
                    const unsigned* r0 = kq + (size_t)col[e] * NF;
                    unsigned ua = r0[l], ub = r0[l + 64];
                    da0 += lo_bf(ua); qa0 += hi_bf(ua);
                    db0 += lo_bf(ub); qb0 += hi_bf(ub);
                }
                da0 += da1; qa0 += qa1; db0 += db1; qb0 += qb1;
                if (e1 > e0) { x0 = qa0 / da0; x1 = qb0 / db0; }
                x0 += feat[(size_t)n * NF + l];
                x1 += feat[(size_t)n * NF + l + 64];
            }
            float S = x0 + x1, Q = x0 * x0 + x1 * x1;
            #pragma unroll
            for (int o = 1; o < 64; o <<= 1) {
                S += __shfl_xor(S, o);
                Q += __shfl_xor(Q, o);
            }
            float mean = S * (1.f / NF);
            float msq  = Q * (1.f / NF);
            float rs   = rsqrtf(msq - mean * mean + LN_EPS);
            float v0 = (x0 - mean) * rs * ga + ba;
            float v1 = (x1 - mean) * rs * gb + bb;
            if (n >= N) { v0 = 0.f; v1 = 0.f; }
            const int sw = (row & 7) << 4;
            *(unsigned short*)(hxb + row * 256 + ((l * 2) ^ sw))         = f2bf(v0);
            *(unsigned short*)(hxb + row * 256 + (((l + 64) * 2) ^ sw))  = f2bf(v1);
        }
    }
    __syncthreads();

    // ---- Phase B: GEMM1 rows n0..+31, wave cols wid*128..+128
    f32x4 acc[2][8];
    #pragma unroll
    for (int mf = 0; mf < 2; ++mf)
        #pragma unroll
        for (int nt = 0; nt < 8; ++nt)
            acc[mf][nt] = (f32x4){0.f, 0.f, 0.f, 0.f};

    #pragma unroll
    for (int kt = 0; kt < 4; ++kt) {
        const int cb = kt * 64 + lg * 16;
        const int sw = (l15 & 7) << 4;
        short8 a0 = *(const short8*)(hxb + l15 * 256        + (cb ^ sw));
        short8 a1 = *(const short8*)(hxb + (16 + l15) * 256 + (cb ^ sw));
        #pragma unroll
        for (int nt = 0; nt < 8; ++nt) {
            short8 b = *(const short8*)(W1f + ((kt * 32 + wid * 8 + nt) * 64 + l) * 8);
            acc[0][nt] = __builtin_amdgcn_mfma_f32_16x16x32_bf16(a0, b, acc[0][nt], 0, 0, 0);
            acc[1][nt] = __builtin_amdgcn_mfma_f32_16x16x32_bf16(a1, b, acc[1][nt], 0, 0, 0);
        }
    }

    // ---- + b1, PReLU -> hlds (global-j swizzled)
    #pragma unroll
    for (int nt = 0; nt < 8; ++nt) {
        int j = wid * 128 + nt * 16 + l15;    // 0..511
        float b1j = b1[j], alj = alpha[j];
        #pragma unroll
        for (int mf = 0; mf < 2; ++mf) {
            #pragma unroll
            for (int r = 0; r < 4; ++r) {
                int row = mf * 16 + lg * 4 + r;
                float hv = acc[mf][nt][r] + b1j;
                hv = hv > 0.f ? hv : alj * hv;
                int byte = row * 1024 + ((j * 2) ^ ((row & 7) << 4));
                *(unsigned short*)(hbase + byte) = f2bf(hv);
            }
        }
    }
    __syncthreads();

    // ---- Phase C: GEMM2 all rows, wave cols wid*32..+32, K = 512
    const int c0 = wid * 32 + l15;
    const int c1 = c0 + 16;
    const float b20 = b2[c0],  b21 = b2[c1];
    const float gg0 = ln_g[c0], gg1 = ln_g[c1];
    const float bb0 = ln_b[c0], bb1 = ln_b[c1];

    f32x4 acc2[2][2];
    #pragma unroll
    for (int mf = 0; mf < 2; ++mf)
        #pragma unroll
        for (int nt = 0; nt < 2; ++nt)
            acc2[mf][nt] = (f32x4){0.f, 0.f, 0.f, 0.f};

    #pragma unroll
    for (int kt = 0; kt < 16; ++kt) {
        int jb = kt * 64 + lg * 16;
        int row0 = l15, row1 = 16 + l15;
        short8 a0 = *(const short8*)(hbase + row0 * 1024 + (jb ^ ((row0 & 7) << 4)));
        short8 a1 = *(const short8*)(hbase + row1 * 1024 + (jb ^ ((row1 & 7) << 4)));
        #pragma unroll
        for (int nt = 0; nt < 2; ++nt) {
            short8 b = *(const short8*)(W2f + ((kt * 8 + wid * 2 + nt) * 64 + l) * 8);
            acc2[0][nt] = __builtin_amdgcn_mfma_f32_16x16x32_bf16(a0, b, acc2[0][nt], 0, 0, 0);
            acc2[1][nt] = __builtin_amdgcn_mfma_f32_16x16x32_bf16(a1, b, acc2[1][nt], 0, 0, 0);
        }
    }

    // ---- y = ffn + b2 + residual(hx); in-wave partial sums -> sred
    float y0[2][4], y1[2][4];
    #pragma unroll
    for (int mf = 0; mf < 2; ++mf) {
        #pragma unroll
        for (int r = 0; r < 4; ++r) {
            int row = mf * 16 + lg * 4 + r;
            int sw = (row & 7) << 4;
            float xr0 = bf2f(*(const unsigned short*)(hxb + row * 256 + ((c0 * 2) ^ sw)));
            float xr1 = bf2f(*(const unsigned short*)(hxb + row * 256 + ((c1 * 2) ^ sw)));
            float a = acc2[mf][0][r] + b20 + xr0;
            float b = acc2[mf][1][r] + b21 + xr1;
            y0[mf][r] = a; y1[mf][r] = b;
            float p1 = a + b, p2 = a * a + b * b;
            #pragma unroll
            for (int o = 1; o < 16; o <<= 1) {
                p1 += __shfl_xor(p1, o);
                p2 += __shfl_xor(p2, o);
            }
            if (l15 == 0) { sredS[row][wid] = p1; sredQ[row][wid] = p2; }
        }
    }
    __syncthreads();

    // ---- LN2 finalize + store
    #pragma unroll
    for (int mf = 0; mf < 2; ++mf) {
        #pragma unroll
        for (int r = 0; r < 4; ++r) {
            int row = mf * 16 + lg * 4 + r;
            int n = n0 + row;
            float S = sredS[row][0] + sredS[row][1] + sredS[row][2] + sredS[row][3];
            float Q = sredQ[row][0] + sredQ[row][1] + sredQ[row][2] + sredQ[row][3];
            float mean = S * (1.f / NF);
            float msq  = Q * (1.f / NF);
            float rs   = rsqrtf(msq - mean * mean + LN_EPS);
            if (n < N) {
                out[(size_t)n * NF + c0] = (y0[mf][r] - mean) * rs * gg0 + bb0;
                out[(size_t)n * NF + c1] = (y1[mf][r] - mean) * rs * gg1 + bb1;
            }
        }
    }
}

// ---------------------------------------------------------------------------
extern "C" void kernel_launch(void* const* d_in, const int* in_sizes, int n_in,
                              void* d_out, int out_size, void* d_ws, size_t ws_size,
                              hipStream_t stream)
{
    const float* feat  = (const float*)d_in[0];
    const float* Wq    = (const float*)d_in[1];
    const float* Wk    = (const float*)d_in[2];
    // d_in[3] = Wv — cancels in per-channel edge softmax, unused.
    const float* ln_g  = (const float*)d_in[4];
    const float* ln_b  = (const float*)d_in[5];
    const float* W1    = (const float*)d_in[6];
    const float* b1    = (const float*)d_in[7];
    const float* alpha = (const float*)d_in[8];
    const float* W2    = (const float*)d_in[9];
    const float* b2    = (const float*)d_in[10];
    const int*   src   = (const int*)d_in[11];
    const int*   dst   = (const int*)d_in[12];

    const int N = in_sizes[0] / NF;
    const int E = in_sizes[11];
    float* out = (float*)d_out;

    char* p = (char*)d_ws;
    unsigned*       kq   = (unsigned*)p;       p += (size_t)N * NF * 4;
    unsigned short* W1f  = (unsigned short*)p; p += (size_t)NF * FH * 2;
    unsigned short* W2f  = (unsigned short*)p; p += (size_t)FH * NF * 2;
    unsigned short* Wqhi = (unsigned short*)p; p += (size_t)NF * NF * 2;
    unsigned short* Wqlo = (unsigned short*)p; p += (size_t)NF * NF * 2;
    unsigned short* Wkhi = (unsigned short*)p; p += (size_t)NF * NF * 2;
    unsigned short* Wklo = (unsigned short*)p; p += (size_t)NF * NF * 2;
    int* deg    = (int*)p;  p += (size_t)N * 4;
    int* off    = (int*)p;  p += (size_t)(N + 1) * 4;
    int* bsum   = (int*)p;  p += 64 * 4;
    int* cursor = (int*)p;  p += (size_t)N * 4;
    int* col    = (int*)p;

    const int nb = (N + 1023) / 1024;

    hipMemsetAsync(deg, 0, (size_t)N * sizeof(int), stream);

    prep_w<<<256, 256, 0, stream>>>(W1, W2, Wq, Wk, W1f, W2f,
                                    Wqhi, Wqlo, Wkhi, Wklo);
    qk_mfma<<<(N + 31) / 32, 256, 0, stream>>>(feat, Wqhi, Wqlo, Wkhi, Wklo,
                                               kq, N);
    hist_kernel<<<(E + 255) / 256, 256, 0, stream>>>(dst, deg, E);
    scan_blk<<<nb, 1024, 0, stream>>>(deg, off, bsum, N);
    scan_mid<<<1, 64, 0, stream>>>(bsum, nb);
    scan_add<<<nb, 1024, 0, stream>>>(off, cursor, bsum, N, E);
    scatter_kernel<<<(E + 255) / 256, 256, 0, stream>>>(src, dst, cursor, col, E);
    sort_csr<<<(N + 3) / 4, 256, 0, stream>>>(off, col, N);
    gfn_fused<<<(N + 31) / 32, 256, 0, stream>>>(feat, kq, off, col, ln_g, ln_b,
                                                 W1f, W2f, b1, alpha, b2, out, N);
}

// Round 12
// 247.422 us; speedup vs baseline: 1.5172x; 1.5172x over previous
//
#include <hip/hip_runtime.h>
#include <math.h>

#define NF 128
#define FH 512
#define SQRT_DH 5.656854249492380f
#define LN_EPS 1e-5f

typedef __attribute__((ext_vector_type(8))) short short8;
typedef __attribute__((ext_vector_type(4))) float f32x4;

__device__ __forceinline__ unsigned short f2bf(float x) {
    union { float f; unsigned u; } c; c.f = x;
    unsigned u = c.u;
    return (unsigned short)((u + 0x7fffu + ((u >> 16) & 1u)) >> 16);
}
__device__ __forceinline__ float bf2f(unsigned short h) {
    union { unsigned u; float f; } c; c.u = (unsigned)h << 16; return c.f;
}
__device__ __forceinline__ float lo_bf(unsigned u) {
    union { unsigned u; float f; } c; c.u = u << 16; return c.f;
}
__device__ __forceinline__ float hi_bf(unsigned u) {
    union { unsigned u; float f; } c; c.u = u & 0xffff0000u; return c.f;
}

// ---------------- weight prep ------------------------------------------------
// B-fragment order: frag[kt][nt][lane][i] = W[kt*32 + (lane>>4)*8 + i][nt*16 + (lane&15)]
__global__ __launch_bounds__(256) void prep_w(
    const float* __restrict__ W1, const float* __restrict__ W2,
    const float* __restrict__ Wq, const float* __restrict__ Wk,
    unsigned short* __restrict__ W1f, unsigned short* __restrict__ W2f,
    unsigned short* __restrict__ Wqhi, unsigned short* __restrict__ Wqlo,
    unsigned short* __restrict__ Wkhi, unsigned short* __restrict__ Wklo)
{
    int f = blockIdx.x * 256 + threadIdx.x;   // 0..65535
    int i = f & 7, l = (f >> 3) & 63;
    int lg = l >> 4, l15 = l & 15;
    {
        int ntg = (f >> 9) & 31, kt = f >> 14;
        int k = kt * 32 + lg * 8 + i, n = ntg * 16 + l15;
        W1f[f] = f2bf(W1[k * FH + n]);
    }
    {
        int nt2 = (f >> 9) & 7, kt2 = f >> 12;
        int k = kt2 * 32 + lg * 8 + i, n = nt2 * 16 + l15;
        W2f[f] = f2bf(W2[k * NF + n]);
    }
    if (f < 16384) {
        int nt = (f >> 9) & 7, kt = f >> 12;
        int k = kt * 32 + lg * 8 + i, n = nt * 16 + l15;
        float vq = Wq[k * NF + n];
        unsigned short qh = f2bf(vq);
        Wqhi[f] = qh; Wqlo[f] = f2bf(vq - bf2f(qh));
        float vk = Wk[k * NF + n];
        unsigned short kh = f2bf(vk);
        Wkhi[f] = kh; Wklo[f] = f2bf(vk - bf2f(kh));
    }
}

// ---------------- Kernel 1: q/k projections via MFMA (hi/lo split) ----------
__global__ __launch_bounds__(256) void qk_mfma(
    const float* __restrict__ feat,
    const unsigned short* __restrict__ Wqhi, const unsigned short* __restrict__ Wqlo,
    const unsigned short* __restrict__ Wkhi, const unsigned short* __restrict__ Wklo,
    unsigned* __restrict__ kq, int N)
{
    const int tid = threadIdx.x;
    const int l = tid & 63, wid = tid >> 6;
    const int l15 = l & 15, lg = l >> 4;
    const int n0 = blockIdx.x * 32;

    f32x4 accq[2][2], acck[2][2];
    #pragma unroll
    for (int mf = 0; mf < 2; ++mf)
        #pragma unroll
        for (int nt = 0; nt < 2; ++nt) {
            accq[mf][nt] = (f32x4){0.f, 0.f, 0.f, 0.f};
            acck[mf][nt] = (f32x4){0.f, 0.f, 0.f, 0.f};
        }

    #pragma unroll
    for (int kt = 0; kt < 4; ++kt) {
        short8 ahi[2], alo[2];
        #pragma unroll
        for (int mf = 0; mf < 2; ++mf) {
            int n = n0 + mf * 16 + l15;
            float v[8];
            if (n < N) {
                const float4* p = (const float4*)(feat + (size_t)n * NF + kt * 32 + lg * 8);
                float4 v0 = p[0], v1 = p[1];
                v[0] = v0.x; v[1] = v0.y; v[2] = v0.z; v[3] = v0.w;
                v[4] = v1.x; v[5] = v1.y; v[6] = v1.z; v[7] = v1.w;
            } else {
                #pragma unroll
                for (int i = 0; i < 8; ++i) v[i] = 0.f;
            }
            #pragma unroll
            for (int i = 0; i < 8; ++i) {
                unsigned short h = f2bf(v[i]);
                ahi[mf][i] = (short)h;
                alo[mf][i] = (short)f2bf(v[i] - bf2f(h));
            }
        }
        #pragma unroll
        for (int nt = 0; nt < 2; ++nt) {
            int ntg = wid * 2 + nt;
            size_t fo = ((size_t)(kt * 8 + ntg) * 64 + l) * 8;
            short8 bqh = *(const short8*)(Wqhi + fo);
            short8 bql = *(const short8*)(Wqlo + fo);
            short8 bkh = *(const short8*)(Wkhi + fo);
            short8 bkl = *(const short8*)(Wklo + fo);
            #pragma unroll
            for (int mf = 0; mf < 2; ++mf) {
                accq[mf][nt] = __builtin_amdgcn_mfma_f32_16x16x32_bf16(ahi[mf], bqh, accq[mf][nt], 0, 0, 0);
                accq[mf][nt] = __builtin_amdgcn_mfma_f32_16x16x32_bf16(alo[mf], bqh, accq[mf][nt], 0, 0, 0);
                accq[mf][nt] = __builtin_amdgcn_mfma_f32_16x16x32_bf16(ahi[mf], bql, accq[mf][nt], 0, 0, 0);
                acck[mf][nt] = __builtin_amdgcn_mfma_f32_16x16x32_bf16(ahi[mf], bkh, acck[mf][nt], 0, 0, 0);
                acck[mf][nt] = __builtin_amdgcn_mfma_f32_16x16x32_bf16(alo[mf], bkh, acck[mf][nt], 0, 0, 0);
                acck[mf][nt] = __builtin_amdgcn_mfma_f32_16x16x32_bf16(ahi[mf], bkl, acck[mf][nt], 0, 0, 0);
            }
        }
    }

    #pragma unroll
    for (int mf = 0; mf < 2; ++mf) {
        #pragma unroll
        for (int nt = 0; nt < 2; ++nt) {
            int colg = wid * 32 + nt * 16 + l15;
            #pragma unroll
            for (int r = 0; r < 4; ++r) {
                int n = n0 + mf * 16 + lg * 4 + r;
                if (n < N) {
                    float kk = acck[mf][nt][r];
                    float qq = accq[mf][nt][r];
                    float e = __expf(SQRT_DH * kk);
                    kq[(size_t)n * NF + colg] =
                        ((unsigned)f2bf(qq * e) << 16) | (unsigned)f2bf(e);
                }
            }
        }
    }
}

// ---------------- CSR build ------------------------------------------------
__global__ __launch_bounds__(256) void hist_kernel(
    const int* __restrict__ dst, int* __restrict__ deg, int E)
{
    int i = blockIdx.x * 256 + threadIdx.x;
    if (i < E) atomicAdd(&deg[dst[i]], 1);
}

__global__ __launch_bounds__(1024) void scan_blk(
    const int* __restrict__ deg, int* __restrict__ off,
    int* __restrict__ bsum, int N)
{
    __shared__ int ws[16];
    const int tid = threadIdx.x, lane = tid & 63, w = tid >> 6;
    int i = blockIdx.x * 1024 + tid;
    int v = (i < N) ? deg[i] : 0;
    int x = v;
    #pragma unroll
    for (int o = 1; o < 64; o <<= 1) {
        int t = __shfl_up(x, o);
        if (lane >= o) x += t;
    }
    if (lane == 63) ws[w] = x;
    __syncthreads();
    if (w == 0 && lane < 16) {
        int s = ws[lane];
        #pragma unroll
        for (int o = 1; o < 16; o <<= 1) {
            int t = __shfl_up(s, o);
            if (lane >= o) s += t;
        }
        ws[lane] = s;
    }
    __syncthreads();
    int wbase = (w == 0) ? 0 : ws[w - 1];
    int incl = wbase + x;
    if (i < N) off[i] = incl - v;
    if (tid == 1023) bsum[blockIdx.x] = incl;
}

__global__ __launch_bounds__(64) void scan_mid(int* __restrict__ bsum, int nb)
{
    int lane = threadIdx.x;
    int v = (lane < nb) ? bsum[lane] : 0;
    int x = v;
    #pragma unroll
    for (int o = 1; o < 64; o <<= 1) {
        int t = __shfl_up(x, o);
        if (lane >= o) x += t;
    }
    if (lane < nb) bsum[lane] = x - v;
}

__global__ __launch_bounds__(1024) void scan_add(
    int* __restrict__ off, int* __restrict__ cursor,
    const int* __restrict__ bsum, int N, int E)
{
    int i = blockIdx.x * 1024 + threadIdx.x;
    if (i < N) {
        int o = off[i] + bsum[blockIdx.x];
        off[i] = o; cursor[i] = o;
    }
    if (i == 0) off[N] = E;
}

__global__ __launch_bounds__(256) void scatter_kernel(
    const int* __restrict__ src, const int* __restrict__ dst,
    int* __restrict__ cursor, int* __restrict__ col, int E)
{
    int i = blockIdx.x * 256 + threadIdx.x;
    if (i < E) {
        int pos = atomicAdd(&cursor[dst[i]], 1);
        col[pos] = src[i];
    }
}

// canonicalize segment order: one wave per node, 64-lane bitonic via shfl_xor
__global__ __launch_bounds__(256) void sort_csr(
    const int* __restrict__ off, int* __restrict__ col, int N)
{
    const int wid  = threadIdx.x >> 6;
    const int lane = threadIdx.x & 63;
    const int n = blockIdx.x * 4 + wid;
    if (n >= N) return;
    const int e0 = off[n], e1 = off[n + 1];
    const int len = e1 - e0;
    if (len <= 1) return;
    if (len <= 64) {
        int v = (lane < len) ? col[e0 + lane] : 0x7fffffff;
        #pragma unroll
        for (int k = 2; k <= 64; k <<= 1) {
            #pragma unroll
            for (int j = k >> 1; j > 0; j >>= 1) {
                int other = __shfl_xor(v, j);
                bool keepMin = (((lane & j) == 0) == ((lane & k) == 0));
                v = keepMin ? (v < other ? v : other)
                            : (v > other ? v : other);
            }
        }
        if (lane < len) col[e0 + lane] = v;
    } else if (lane == 0) {
        for (int i = e0 + 1; i < e1; ++i) {
            int v = col[i];
            int j = i - 1;
            while (j >= e0 && col[j] > v) { col[j + 1] = col[j]; --j; }
            col[j + 1] = v;
        }
    }
}

// ---------------- gather + residual + LN1 -> xb (bf16), xf (fp32) ----------
// grid covers Npad rows; rows >= N are written as zeros (deterministic pad).
__global__ __launch_bounds__(128) void gather_ln1(
    const float* __restrict__ feat, const unsigned* __restrict__ kq,
    const int* __restrict__ off, const int* __restrict__ col,
    const float* __restrict__ ln_g, const float* __restrict__ ln_b,
    unsigned short* __restrict__ xb, float* __restrict__ xf, int N)
{
    __shared__ float sred[2][2];
    const int tid = threadIdx.x;
    const int lane = tid & 63;
    const int wv = tid >> 6;
    const int n0 = blockIdx.x * 8;

    const float gg = ln_g[tid];
    const float bb = ln_b[tid];

    for (int m = 0; m < 8; ++m) {
        int n = n0 + m;
        float xr = 0.f;
        bool valid = (n < N);
        if (valid) {
            int e0 = off[n], e1 = off[n + 1];
            float d0 = 0.f, q0 = 0.f, d1 = 0.f, q1 = 0.f;
            float d2 = 0.f, q2 = 0.f, d3 = 0.f, q3 = 0.f;
            int e = e0;
            for (; e + 3 < e1; e += 4) {
                unsigned u0 = kq[(size_t)col[e]     * NF + tid];
                unsigned u1 = kq[(size_t)col[e + 1] * NF + tid];
                unsigned u2 = kq[(size_t)col[e + 2] * NF + tid];
                unsigned u3 = kq[(size_t)col[e + 3] * NF + tid];
                d0 += lo_bf(u0); q0 += hi_bf(u0);
                d1 += lo_bf(u1); q1 += hi_bf(u1);
                d2 += lo_bf(u2); q2 += hi_bf(u2);
                d3 += lo_bf(u3); q3 += hi_bf(u3);
            }
            for (; e < e1; ++e) {
                unsigned u = kq[(size_t)col[e] * NF + tid];
                d0 += lo_bf(u); q0 += hi_bf(u);
            }
            d0 += d1 + d2 + d3; q0 += q1 + q2 + q3;
            float ag = (e1 > e0) ? q0 / d0 : 0.f;
            xr = ag + feat[(size_t)n * NF + tid];
        }
        float s1 = xr, s2 = xr * xr;
        #pragma unroll
        for (int o = 32; o > 0; o >>= 1) {
            s1 += __shfl_down(s1, o);
            s2 += __shfl_down(s2, o);
        }
        if (lane == 0) { sred[0][wv] = s1; sred[1][wv] = s2; }
        __syncthreads();
        float mean = (sred[0][0] + sred[0][1]) * (1.f / NF);
        float msq  = (sred[1][0] + sred[1][1]) * (1.f / NF);
        float rs   = rsqrtf(msq - mean * mean + LN_EPS);
        float xv   = valid ? ((xr - mean) * rs * gg + bb) : 0.f;
        xb[(size_t)n * NF + tid] = f2bf(xv);
        xf[(size_t)n * NF + tid] = xv;
        __syncthreads();
    }
}

// ---------------- fused FFN v6: BM=16 (more blocks -> more TLP) ------------
// GEMM1: wave w -> h cols w*128..+128 (acc[8]); h in shared [16][512] bf16,
// XOR-swizzled. GEMM2: wave w -> out cols w*32..+32, all 16 rows, K=512.
// LN2: 16-lane shfl partials -> sred[16][4] -> broadcast. 2 barriers.
__global__ __launch_bounds__(256) void ffn_fused(
    const unsigned short* __restrict__ xb, const float* __restrict__ xf,
    const unsigned short* __restrict__ W1f, const unsigned short* __restrict__ W2f,
    const float* __restrict__ b1, const float* __restrict__ alpha,
    const float* __restrict__ b2,
    const float* __restrict__ ln_g, const float* __restrict__ ln_b,
    float* __restrict__ out, int N)
{
    __shared__ unsigned short hlds[16 * 512];   // 16 KB, swizzled
    __shared__ float sredS[16][4];
    __shared__ float sredQ[16][4];

    const int tid = threadIdx.x;
    const int l = tid & 63;
    const int wid = tid >> 6;
    const int l15 = l & 15;
    const int lg = l >> 4;
    const int n0 = blockIdx.x * 16;

    char* hbase = (char*)hlds;

    // ---- GEMM1: rows n0..n0+15, wave cols wid*128..+128
    f32x4 acc[8];
    #pragma unroll
    for (int nt = 0; nt < 8; ++nt)
        acc[nt] = (f32x4){0.f, 0.f, 0.f, 0.f};

    #pragma unroll
    for (int kt = 0; kt < 4; ++kt) {
        short8 a0 = *(const short8*)(xb + (size_t)(n0 + l15) * NF + kt * 32 + lg * 8);
        #pragma unroll
        for (int nt = 0; nt < 8; ++nt) {
            short8 b = *(const short8*)(W1f + ((kt * 32 + wid * 8 + nt) * 64 + l) * 8);
            acc[nt] = __builtin_amdgcn_mfma_f32_16x16x32_bf16(a0, b, acc[nt], 0, 0, 0);
        }
    }

    // ---- epilogue: + b1, PReLU, -> hlds (global-j swizzled)
    #pragma unroll
    for (int nt = 0; nt < 8; ++nt) {
        int j = wid * 128 + nt * 16 + l15;    // 0..511
        float b1j = b1[j], alj = alpha[j];
        #pragma unroll
        for (int r = 0; r < 4; ++r) {
            int row = lg * 4 + r;
            float hv = acc[nt][r] + b1j;
            hv = hv > 0.f ? hv : alj * hv;
            int byte = row * 1024 + ((j * 2) ^ ((row & 7) << 4));
            *(unsigned short*)(hbase + byte) = f2bf(hv);
        }
    }
    __syncthreads();

    // ---- prefetch LN2 params + residual (overlaps GEMM2 MFMA)
    const int c0 = wid * 32 + l15;
    const int c1 = c0 + 16;
    const float b20 = b2[c0],  b21 = b2[c1];
    const float gg0 = ln_g[c0], gg1 = ln_g[c1];
    const float bb0 = ln_b[c0], bb1 = ln_b[c1];
    float xv0[4], xv1[4];
    #pragma unroll
    for (int r = 0; r < 4; ++r) {
        size_t n = (size_t)(n0 + lg * 4 + r);
        xv0[r] = xf[n * NF + c0];
        xv1[r] = xf[n * NF + c1];
    }

    // ---- GEMM2: all 16 rows, wave cols wid*32..+32, K = 512
    f32x4 acc2[2];
    #pragma unroll
    for (int nt = 0; nt < 2; ++nt)
        acc2[nt] = (f32x4){0.f, 0.f, 0.f, 0.f};

    #pragma unroll
    for (int kt = 0; kt < 16; ++kt) {
        int jb = kt * 64 + lg * 16;
        int row0 = l15;
        short8 a0 = *(const short8*)(hbase + row0 * 1024 + (jb ^ ((row0 & 7) << 4)));
        #pragma unroll
        for (int nt = 0; nt < 2; ++nt) {
            short8 b = *(const short8*)(W2f + ((kt * 8 + wid * 2 + nt) * 64 + l) * 8);
            acc2[nt] = __builtin_amdgcn_mfma_f32_16x16x32_bf16(a0, b, acc2[nt], 0, 0, 0);
        }
    }

    // ---- y = ffn + b2 + x; in-wave partial sums -> sred
    float y0[4], y1[4];
    #pragma unroll
    for (int r = 0; r < 4; ++r) {
        int row = lg * 4 + r;
        float a = acc2[0][r] + b20 + xv0[r];
        float b = acc2[1][r] + b21 + xv1[r];
        y0[r] = a; y1[r] = b;
        float p1 = a + b, p2 = a * a + b * b;
        #pragma unroll
        for (int o = 1; o < 16; o <<= 1) {
            p1 += __shfl_xor(p1, o);
            p2 += __shfl_xor(p2, o);
        }
        if (l15 == 0) { sredS[row][wid] = p1; sredQ[row][wid] = p2; }
    }
    __syncthreads();

    // ---- LN2 finalize + store
    #pragma unroll
    for (int r = 0; r < 4; ++r) {
        int row = lg * 4 + r;
        int n = n0 + row;
        float S = sredS[row][0] + sredS[row][1] + sredS[row][2] + sredS[row][3];
        float Q = sredQ[row][0] + sredQ[row][1] + sredQ[row][2] + sredQ[row][3];
        float mean = S * (1.f / NF);
        float msq  = Q * (1.f / NF);
        float rs   = rsqrtf(msq - mean * mean + LN_EPS);
        if (n < N) {
            out[(size_t)n * NF + c0] = (y0[r] - mean) * rs * gg0 + bb0;
            out[(size_t)n * NF + c1] = (y1[r] - mean) * rs * gg1 + bb1;
        }
    }
}

// ---------------------------------------------------------------------------
extern "C" void kernel_launch(void* const* d_in, const int* in_sizes, int n_in,
                              void* d_out, int out_size, void* d_ws, size_t ws_size,
                              hipStream_t stream)
{
    const float* feat  = (const float*)d_in[0];
    const float* Wq    = (const float*)d_in[1];
    const float* Wk    = (const float*)d_in[2];
    // d_in[3] = Wv — cancels in per-channel edge softmax, unused.
    const float* ln_g  = (const float*)d_in[4];
    const float* ln_b  = (const float*)d_in[5];
    const float* W1    = (const float*)d_in[6];
    const float* b1    = (const float*)d_in[7];
    const float* alpha = (const float*)d_in[8];
    const float* W2    = (const float*)d_in[9];
    const float* b2    = (const float*)d_in[10];
    const int*   src   = (const int*)d_in[11];
    const int*   dst   = (const int*)d_in[12];

    const int N = in_sizes[0] / NF;
    const int E = in_sizes[11];
    const int Npad = ((N + 63) / 64) * 64;
    float* out = (float*)d_out;

    char* p = (char*)d_ws;
    unsigned*       kq  = (unsigned*)p;       p += (size_t)N * NF * 4;
    unsigned short* xb  = (unsigned short*)p; p += (size_t)Npad * NF * 2;
    float*          xf  = (float*)p;          p += (size_t)Npad * NF * 4;
    unsigned short* W1f = (unsigned short*)p; p += (size_t)NF * FH * 2;
    unsigned short* W2f = (unsigned short*)p; p += (size_t)FH * NF * 2;
    unsigned short* Wqhi = (unsigned short*)p; p += (size_t)NF * NF * 2;
    unsigned short* Wqlo = (unsigned short*)p; p += (size_t)NF * NF * 2;
    unsigned short* Wkhi = (unsigned short*)p; p += (size_t)NF * NF * 2;
    unsigned short* Wklo = (unsigned short*)p; p += (size_t)NF * NF * 2;
    int* deg    = (int*)p;  p += (size_t)N * 4;
    int* off    = (int*)p;  p += (size_t)(N + 1) * 4;
    int* bsum   = (int*)p;  p += 64 * 4;
    int* cursor = (int*)p;  p += (size_t)N * 4;
    int* col    = (int*)p;

    const int nb = (N + 1023) / 1024;

    hipMemsetAsync(deg, 0, (size_t)N * sizeof(int), stream);

    prep_w<<<256, 256, 0, stream>>>(W1, W2, Wq, Wk, W1f, W2f,
                                    Wqhi, Wqlo, Wkhi, Wklo);
    qk_mfma<<<(N + 31) / 32, 256, 0, stream>>>(feat, Wqhi, Wqlo, Wkhi, Wklo,
                                               kq, N);
    hist_kernel<<<(E + 255) / 256, 256, 0, stream>>>(dst, deg, E);
    scan_blk<<<nb, 1024, 0, stream>>>(deg, off, bsum, N);
    scan_mid<<<1, 64, 0, stream>>>(bsum, nb);
    scan_add<<<nb, 1024, 0, stream>>>(off, cursor, bsum, N, E);
    scatter_kernel<<<(E + 255) / 256, 256, 0, stream>>>(src, dst, cursor, col, E);
    sort_csr<<<(N + 3) / 4, 256, 0, stream>>>(off, col, N);
    gather_ln1<<<(Npad + 7) / 8, 128, 0, stream>>>(feat, kq, off, col, ln_g, ln_b,
                                                   xb, xf, N);
    ffn_fused<<<(N + 15) / 16, 256, 0, stream>>>(xb, xf, W1f, W2f, b1, alpha,
                                                 b2, ln_g, ln_b, out, N);
}

// Round 13
// 242.587 us; speedup vs baseline: 1.5474x; 1.0199x over previous
//
#include <hip/hip_runtime.h>
#include <math.h>

#define NF 128
#define FH 512
#define SQRT_DH 5.656854249492380f
#define LN_EPS 1e-5f

typedef __attribute__((ext_vector_type(8))) short short8;
typedef __attribute__((ext_vector_type(4))) float f32x4;

__device__ __forceinline__ unsigned short f2bf(float x) {
    union { float f; unsigned u; } c; c.f = x;
    unsigned u = c.u;
    return (unsigned short)((u + 0x7fffu + ((u >> 16) & 1u)) >> 16);
}
__device__ __forceinline__ float bf2f(unsigned short h) {
    union { unsigned u; float f; } c; c.u = (unsigned)h << 16; return c.f;
}
__device__ __forceinline__ float lo_bf(unsigned u) {
    union { unsigned u; float f; } c; c.u = u << 16; return c.f;
}
__device__ __forceinline__ float hi_bf(unsigned u) {
    union { unsigned u; float f; } c; c.u = u & 0xffff0000u; return c.f;
}

// ---------------- weight prep ∥ dst histogram (block-specialized) -----------
// blocks [0,256): weight fragment prep; blocks [256,..): histogram of dst.
__global__ __launch_bounds__(256) void prep_hist(
    const float* __restrict__ W1, const float* __restrict__ W2,
    const float* __restrict__ Wq, const float* __restrict__ Wk,
    unsigned short* __restrict__ W1f, unsigned short* __restrict__ W2f,
    unsigned short* __restrict__ Wqhi, unsigned short* __restrict__ Wqlo,
    unsigned short* __restrict__ Wkhi, unsigned short* __restrict__ Wklo,
    const int* __restrict__ dst, int* __restrict__ deg, int E)
{
    if (blockIdx.x >= 256) {
        int i = (blockIdx.x - 256) * 256 + threadIdx.x;
        if (i < E) atomicAdd(&deg[dst[i]], 1);
        return;
    }
    int f = blockIdx.x * 256 + threadIdx.x;   // 0..65535
    int i = f & 7, l = (f >> 3) & 63;
    int lg = l >> 4, l15 = l & 15;
    {
        int ntg = (f >> 9) & 31, kt = f >> 14;
        int k = kt * 32 + lg * 8 + i, n = ntg * 16 + l15;
        W1f[f] = f2bf(W1[k * FH + n]);
    }
    {
        int nt2 = (f >> 9) & 7, kt2 = f >> 12;
        int k = kt2 * 32 + lg * 8 + i, n = nt2 * 16 + l15;
        W2f[f] = f2bf(W2[k * NF + n]);
    }
    if (f < 16384) {
        int nt = (f >> 9) & 7, kt = f >> 12;
        int k = kt * 32 + lg * 8 + i, n = nt * 16 + l15;
        float vq = Wq[k * NF + n];
        unsigned short qh = f2bf(vq);
        Wqhi[f] = qh; Wqlo[f] = f2bf(vq - bf2f(qh));
        float vk = Wk[k * NF + n];
        unsigned short kh = f2bf(vk);
        Wkhi[f] = kh; Wklo[f] = f2bf(vk - bf2f(kh));
    }
}

// ---------------- q/k projections via MFMA (hi/lo split) --------------------
__global__ __launch_bounds__(256) void qk_mfma(
    const float* __restrict__ feat,
    const unsigned short* __restrict__ Wqhi, const unsigned short* __restrict__ Wqlo,
    const unsigned short* __restrict__ Wkhi, const unsigned short* __restrict__ Wklo,
    unsigned* __restrict__ kq, int N)
{
    const int tid = threadIdx.x;
    const int l = tid & 63, wid = tid >> 6;
    const int l15 = l & 15, lg = l >> 4;
    const int n0 = blockIdx.x * 32;

    f32x4 accq[2][2], acck[2][2];
    #pragma unroll
    for (int mf = 0; mf < 2; ++mf)
        #pragma unroll
        for (int nt = 0; nt < 2; ++nt) {
            accq[mf][nt] = (f32x4){0.f, 0.f, 0.f, 0.f};
            acck[mf][nt] = (f32x4){0.f, 0.f, 0.f, 0.f};
        }

    #pragma unroll
    for (int kt = 0; kt < 4; ++kt) {
        short8 ahi[2], alo[2];
        #pragma unroll
        for (int mf = 0; mf < 2; ++mf) {
            int n = n0 + mf * 16 + l15;
            float v[8];
            if (n < N) {
                const float4* p = (const float4*)(feat + (size_t)n * NF + kt * 32 + lg * 8);
                float4 v0 = p[0], v1 = p[1];
                v[0] = v0.x; v[1] = v0.y; v[2] = v0.z; v[3] = v0.w;
                v[4] = v1.x; v[5] = v1.y; v[6] = v1.z; v[7] = v1.w;
            } else {
                #pragma unroll
                for (int i = 0; i < 8; ++i) v[i] = 0.f;
            }
            #pragma unroll
            for (int i = 0; i < 8; ++i) {
                unsigned short h = f2bf(v[i]);
                ahi[mf][i] = (short)h;
                alo[mf][i] = (short)f2bf(v[i] - bf2f(h));
            }
        }
        #pragma unroll
        for (int nt = 0; nt < 2; ++nt) {
            int ntg = wid * 2 + nt;
            size_t fo = ((size_t)(kt * 8 + ntg) * 64 + l) * 8;
            short8 bqh = *(const short8*)(Wqhi + fo);
            short8 bql = *(const short8*)(Wqlo + fo);
            short8 bkh = *(const short8*)(Wkhi + fo);
            short8 bkl = *(const short8*)(Wklo + fo);
            #pragma unroll
            for (int mf = 0; mf < 2; ++mf) {
                accq[mf][nt] = __builtin_amdgcn_mfma_f32_16x16x32_bf16(ahi[mf], bqh, accq[mf][nt], 0, 0, 0);
                accq[mf][nt] = __builtin_amdgcn_mfma_f32_16x16x32_bf16(alo[mf], bqh, accq[mf][nt], 0, 0, 0);
                accq[mf][nt] = __builtin_amdgcn_mfma_f32_16x16x32_bf16(ahi[mf], bql, accq[mf][nt], 0, 0, 0);
                acck[mf][nt] = __builtin_amdgcn_mfma_f32_16x16x32_bf16(ahi[mf], bkh, acck[mf][nt], 0, 0, 0);
                acck[mf][nt] = __builtin_amdgcn_mfma_f32_16x16x32_bf16(alo[mf], bkh, acck[mf][nt], 0, 0, 0);
                acck[mf][nt] = __builtin_amdgcn_mfma_f32_16x16x32_bf16(ahi[mf], bkl, acck[mf][nt], 0, 0, 0);
            }
        }
    }

    #pragma unroll
    for (int mf = 0; mf < 2; ++mf) {
        #pragma unroll
        for (int nt = 0; nt < 2; ++nt) {
            int colg = wid * 32 + nt * 16 + l15;
            #pragma unroll
            for (int r = 0; r < 4; ++r) {
                int n = n0 + mf * 16 + lg * 4 + r;
                if (n < N) {
                    float kk = acck[mf][nt][r];
                    float qq = accq[mf][nt][r];
                    float e = __expf(SQRT_DH * kk);
                    kq[(size_t)n * NF + colg] =
                        ((unsigned)f2bf(qq * e) << 16) | (unsigned)f2bf(e);
                }
            }
        }
    }
}

// ---------------- CSR build ------------------------------------------------
__global__ __launch_bounds__(1024) void scan_blk(
    const int* __restrict__ deg, int* __restrict__ off,
    int* __restrict__ bsum, int N)
{
    __shared__ int ws[16];
    const int tid = threadIdx.x, lane = tid & 63, w = tid >> 6;
    int i = blockIdx.x * 1024 + tid;
    int v = (i < N) ? deg[i] : 0;
    int x = v;
    #pragma unroll
    for (int o = 1; o < 64; o <<= 1) {
        int t = __shfl_up(x, o);
        if (lane >= o) x += t;
    }
    if (lane == 63) ws[w] = x;
    __syncthreads();
    if (w == 0 && lane < 16) {
        int s = ws[lane];
        #pragma unroll
        for (int o = 1; o < 16; o <<= 1) {
            int t = __shfl_up(s, o);
            if (lane >= o) s += t;
        }
        ws[lane] = s;
    }
    __syncthreads();
    int wbase = (w == 0) ? 0 : ws[w - 1];
    int incl = wbase + x;
    if (i < N) off[i] = incl - v;
    if (tid == 1023) bsum[blockIdx.x] = incl;
}

__global__ __launch_bounds__(64) void scan_mid(int* __restrict__ bsum, int nb)
{
    int lane = threadIdx.x;
    int v = (lane < nb) ? bsum[lane] : 0;
    int x = v;
    #pragma unroll
    for (int o = 1; o < 64; o <<= 1) {
        int t = __shfl_up(x, o);
        if (lane >= o) x += t;
    }
    if (lane < nb) bsum[lane] = x - v;
}

__global__ __launch_bounds__(1024) void scan_add(
    int* __restrict__ off, int* __restrict__ cursor,
    const int* __restrict__ bsum, int N, int E)
{
    int i = blockIdx.x * 1024 + threadIdx.x;
    if (i < N) {
        int o = off[i] + bsum[blockIdx.x];
        off[i] = o; cursor[i] = o;
    }
    if (i == 0) off[N] = E;
}

__global__ __launch_bounds__(256) void scatter_kernel(
    const int* __restrict__ src, const int* __restrict__ dst,
    int* __restrict__ cursor, int* __restrict__ col, int E)
{
    int i = blockIdx.x * 256 + threadIdx.x;
    if (i < E) {
        int pos = atomicAdd(&cursor[dst[i]], 1);
        col[pos] = src[i];
    }
}

// canonicalize segment order: one wave per node, 64-lane bitonic via shfl_xor
__global__ __launch_bounds__(256) void sort_csr(
    const int* __restrict__ off, int* __restrict__ col, int N)
{
    const int wid  = threadIdx.x >> 6;
    const int lane = threadIdx.x & 63;
    const int n = blockIdx.x * 4 + wid;
    if (n >= N) return;
    const int e0 = off[n], e1 = off[n + 1];
    const int len = e1 - e0;
    if (len <= 1) return;
    if (len <= 64) {
        int v = (lane < len) ? col[e0 + lane] : 0x7fffffff;
        #pragma unroll
        for (int k = 2; k <= 64; k <<= 1) {
            #pragma unroll
            for (int j = k >> 1; j > 0; j >>= 1) {
                int other = __shfl_xor(v, j);
                bool keepMin = (((lane & j) == 0) == ((lane & k) == 0));
                v = keepMin ? (v < other ? v : other)
                            : (v > other ? v : other);
            }
        }
        if (lane < len) col[e0 + lane] = v;
    } else if (lane == 0) {
        for (int i = e0 + 1; i < e1; ++i) {
            int v = col[i];
            int j = i - 1;
            while (j >= e0 && col[j] > v) { col[j + 1] = col[j]; --j; }
            col[j + 1] = v;
        }
    }
}

// ---------------- gather + residual + LN1 (wave-per-node, no barriers) -----
// Lane holds channel pair (2l, 2l+1): one uint2 load per edge per lane.
// LN1 via 64-lane shfl_xor. Grid covers Npad rows (pad rows -> zeros).
__global__ __launch_bounds__(256) void gather_ln1(
    const float* __restrict__ feat, const unsigned* __restrict__ kq,
    const int* __restrict__ off, const int* __restrict__ col,
    const float* __restrict__ ln_g, const float* __restrict__ ln_b,
    unsigned short* __restrict__ xb, float* __restrict__ xf, int N, int Npad)
{
    const int lane = threadIdx.x & 63;
    const int wv   = threadIdx.x >> 6;
    const int n    = blockIdx.x * 4 + wv;
    if (n >= Npad) return;
    const int c0 = lane * 2;

    const float g0 = ln_g[c0], g1 = ln_g[c0 + 1];
    const float bb0 = ln_b[c0], bb1 = ln_b[c0 + 1];

    float x0 = 0.f, x1 = 0.f;
    const bool valid = (n < N);
    if (valid) {
        const int e0 = off[n], e1 = off[n + 1];
        float dA0 = 0.f, qA0 = 0.f, dA1 = 0.f, qA1 = 0.f;
        float dB0 = 0.f, qB0 = 0.f, dB1 = 0.f, qB1 = 0.f;
        float dC0 = 0.f, qC0 = 0.f, dC1 = 0.f, qC1 = 0.f;
        float dD0 = 0.f, qD0 = 0.f, dD1 = 0.f, qD1 = 0.f;
        int e = e0;
        for (; e + 3 < e1; e += 4) {
            uint2 uA = *(const uint2*)(kq + (size_t)col[e]     * NF + c0);
            uint2 uB = *(const uint2*)(kq + (size_t)col[e + 1] * NF + c0);
            uint2 uC = *(const uint2*)(kq + (size_t)col[e + 2] * NF + c0);
            uint2 uD = *(const uint2*)(kq + (size_t)col[e + 3] * NF + c0);
            dA0 += lo_bf(uA.x); qA0 += hi_bf(uA.x); dA1 += lo_bf(uA.y); qA1 += hi_bf(uA.y);
            dB0 += lo_bf(uB.x); qB0 += hi_bf(uB.x); dB1 += lo_bf(uB.y); qB1 += hi_bf(uB.y);
            dC0 += lo_bf(uC.x); qC0 += hi_bf(uC.x); dC1 += lo_bf(uC.y); qC1 += hi_bf(uC.y);
            dD0 += lo_bf(uD.x); qD0 += hi_bf(uD.x); dD1 += lo_bf(uD.y); qD1 += hi_bf(uD.y);
        }
        for (; e < e1; ++e) {
            uint2 u = *(const uint2*)(kq + (size_t)col[e] * NF + c0);
            dA0 += lo_bf(u.x); qA0 += hi_bf(u.x); dA1 += lo_bf(u.y); qA1 += hi_bf(u.y);
        }
        dA0 += dB0 + dC0 + dD0; qA0 += qB0 + qC0 + qD0;
        dA1 += dB1 + dC1 + dD1; qA1 += qB1 + qC1 + qD1;
        if (e1 > e0) { x0 = qA0 / dA0; x1 = qA1 / dA1; }
        const float2 fv = *(const float2*)(feat + (size_t)n * NF + c0);
        x0 += fv.x; x1 += fv.y;
    }
    float S = x0 + x1, Q = x0 * x0 + x1 * x1;
    #pragma unroll
    for (int o = 1; o < 64; o <<= 1) {
        S += __shfl_xor(S, o);
        Q += __shfl_xor(Q, o);
    }
    float mean = S * (1.f / NF);
    float msq  = Q * (1.f / NF);
    float rs   = rsqrtf(msq - mean * mean + LN_EPS);
    float v0 = valid ? ((x0 - mean) * rs * g0 + bb0) : 0.f;
    float v1 = valid ? ((x1 - mean) * rs * g1 + bb1) : 0.f;
    *(unsigned*)(xb + (size_t)n * NF + c0) =
        (unsigned)f2bf(v0) | ((unsigned)f2bf(v1) << 16);
    *(float2*)(xf + (size_t)n * NF + c0) = make_float2(v0, v1);
}

// ---------------- fused FFN v7: BM=32, 8 waves (same per-wave tiling) ------
// GEMM1: wave w -> h cols w*64..+64 (acc[2][4]); hlds [32][512] bf16 swizzled.
// GEMM2: wave w -> out cols w*16..+16, all 32 rows, K=512 (acc2[2]).
// LN2: 16-lane shfl partials -> sred[32][8] -> broadcast. 2 barriers.
__global__ __launch_bounds__(512) void ffn_fused(
    const unsigned short* __restrict__ xb, const float* __restrict__ xf,
    const unsigned short* __restrict__ W1f, const unsigned short* __restrict__ W2f,
    const float* __restrict__ b1, const float* __restrict__ alpha,
    const float* __restrict__ b2,
    const float* __restrict__ ln_g, const float* __restrict__ ln_b,
    float* __restrict__ out, int N)
{
    __shared__ unsigned short hlds[32 * 512];   // 32 KB, swizzled
    __shared__ float sredS[32][8];
    __shared__ float sredQ[32][8];

    const int tid = threadIdx.x;
    const int l = tid & 63;
    const int wid = tid >> 6;          // 0..7
    const int l15 = l & 15;
    const int lg = l >> 4;
    const int n0 = blockIdx.x * 32;

    char* hbase = (char*)hlds;

    // ---- GEMM1: rows n0..n0+31, wave cols wid*64..+64
    f32x4 acc[2][4];
    #pragma unroll
    for (int mf = 0; mf < 2; ++mf)
        #pragma unroll
        for (int nt = 0; nt < 4; ++nt)
            acc[mf][nt] = (f32x4){0.f, 0.f, 0.f, 0.f};

    #pragma unroll
    for (int kt = 0; kt < 4; ++kt) {
        short8 a0 = *(const short8*)(xb + (size_t)(n0 + l15)      * NF + kt * 32 + lg * 8);
        short8 a1 = *(const short8*)(xb + (size_t)(n0 + 16 + l15) * NF + kt * 32 + lg * 8);
        #pragma unroll
        for (int nt = 0; nt < 4; ++nt) {
            short8 b = *(const short8*)(W1f + ((kt * 32 + wid * 4 + nt) * 64 + l) * 8);
            acc[0][nt] = __builtin_amdgcn_mfma_f32_16x16x32_bf16(a0, b, acc[0][nt], 0, 0, 0);
            acc[1][nt] = __builtin_amdgcn_mfma_f32_16x16x32_bf16(a1, b, acc[1][nt], 0, 0, 0);
        }
    }

    // ---- epilogue: + b1, PReLU, -> hlds (global-j swizzled)
    #pragma unroll
    for (int nt = 0; nt < 4; ++nt) {
        int j = wid * 64 + nt * 16 + l15;    // 0..511
        float b1j = b1[j], alj = alpha[j];
        #pragma unroll
        for (int mf = 0; mf < 2; ++mf) {
            #pragma unroll
            for (int r = 0; r < 4; ++r) {
                int row = mf * 16 + lg * 4 + r;
                float hv = acc[mf][nt][r] + b1j;
                hv = hv > 0.f ? hv : alj * hv;
                int byte = row * 1024 + ((j * 2) ^ ((row & 7) << 4));
                *(unsigned short*)(hbase + byte) = f2bf(hv);
            }
        }
    }
    __syncthreads();

    // ---- prefetch LN2 params + residual (overlaps GEMM2 MFMA)
    const int c0 = wid * 16 + l15;     // single out col per lane
    const float b20 = b2[c0];
    const float gg0 = ln_g[c0];
    const float bb0 = ln_b[c0];
    float xv[2][4];
    #pragma unroll
    for (int mf = 0; mf < 2; ++mf)
        #pragma unroll
        for (int r = 0; r < 4; ++r) {
            size_t n = (size_t)(n0 + mf * 16 + lg * 4 + r);
            xv[mf][r] = xf[n * NF + c0];
        }

    // ---- GEMM2: all 32 rows, wave cols wid*16..+16, K = 512
    f32x4 acc2[2];
    acc2[0] = (f32x4){0.f, 0.f, 0.f, 0.f};
    acc2[1] = (f32x4){0.f, 0.f, 0.f, 0.f};

    #pragma unroll
    for (int kt = 0; kt < 16; ++kt) {
        int jb = kt * 64 + lg * 16;
        int row0 = l15, row1 = 16 + l15;
        short8 a0 = *(const short8*)(hbase + row0 * 1024 + (jb ^ ((row0 & 7) << 4)));
        short8 a1 = *(const short8*)(hbase + row1 * 1024 + (jb ^ ((row1 & 7) << 4)));
        short8 b = *(const short8*)(W2f + ((kt * 8 + wid) * 64 + l) * 8);
        acc2[0] = __builtin_amdgcn_mfma_f32_16x16x32_bf16(a0, b, acc2[0], 0, 0, 0);
        acc2[1] = __builtin_amdgcn_mfma_f32_16x16x32_bf16(a1, b, acc2[1], 0, 0, 0);
    }

    // ---- y = ffn + b2 + x; in-wave 16-lane partial sums -> sred
    float y[2][4];
    #pragma unroll
    for (int mf = 0; mf < 2; ++mf) {
        #pragma unroll
        for (int r = 0; r < 4; ++r) {
            int row = mf * 16 + lg * 4 + r;
            float a = acc2[mf][r] + b20 + xv[mf][r];
            y[mf][r] = a;
            float p1 = a, p2 = a * a;
            #pragma unroll
            for (int o = 1; o < 16; o <<= 1) {
                p1 += __shfl_xor(p1, o);
                p2 += __shfl_xor(p2, o);
            }
            if (l15 == 0) { sredS[row][wid] = p1; sredQ[row][wid] = p2; }
        }
    }
    __syncthreads();

    // ---- LN2 finalize + store
    #pragma unroll
    for (int mf = 0; mf < 2; ++mf) {
        #pragma unroll
        for (int r = 0; r < 4; ++r) {
            int row = mf * 16 + lg * 4 + r;
            int n = n0 + row;
            float S = 0.f, Q = 0.f;
            #pragma unroll
            for (int w = 0; w < 8; ++w) { S += sredS[row][w]; Q += sredQ[row][w]; }
            float mean = S * (1.f / NF);
            float msq  = Q * (1.f / NF);
            float rs   = rsqrtf(msq - mean * mean + LN_EPS);
            if (n < N)
                out[(size_t)n * NF + c0] = (y[mf][r] - mean) * rs * gg0 + bb0;
        }
    }
}

// ---------------------------------------------------------------------------
extern "C" void kernel_launch(void* const* d_in, const int* in_sizes, int n_in,
                              void* d_out, int out_size, void* d_ws, size_t ws_size,
                              hipStream_t stream)
{
    const float* feat  = (const float*)d_in[0];
    const float* Wq    = (const float*)d_in[1];
    const float* Wk    = (const float*)d_in[2];
    // d_in[3] = Wv — cancels in per-channel edge softmax, unused.
    const float* ln_g  = (const float*)d_in[4];
    const float* ln_b  = (const float*)d_in[5];
    const float* W1    = (const float*)d_in[6];
    const float* b1    = (const float*)d_in[7];
    const float* alpha = (const float*)d_in[8];
    const float* W2    = (const float*)d_in[9];
    const float* b2    = (const float*)d_in[10];
    const int*   src   = (const int*)d_in[11];
    const int*   dst   = (const int*)d_in[12];

    const int N = in_sizes[0] / NF;
    const int E = in_sizes[11];
    const int Npad = ((N + 63) / 64) * 64;
    float* out = (float*)d_out;

    char* p = (char*)d_ws;
    unsigned*       kq  = (unsigned*)p;       p += (size_t)N * NF * 4;
    unsigned short* xb  = (unsigned short*)p; p += (size_t)Npad * NF * 2;
    float*          xf  = (float*)p;          p += (size_t)Npad * NF * 4;
    unsigned short* W1f = (unsigned short*)p; p += (size_t)NF * FH * 2;
    unsigned short* W2f = (unsigned short*)p; p += (size_t)FH * NF * 2;
    unsigned short* Wqhi = (unsigned short*)p; p += (size_t)NF * NF * 2;
    unsigned short* Wqlo = (unsigned short*)p; p += (size_t)NF * NF * 2;
    unsigned short* Wkhi = (unsigned short*)p; p += (size_t)NF * NF * 2;
    unsigned short* Wklo = (unsigned short*)p; p += (size_t)NF * NF * 2;
    int* deg    = (int*)p;  p += (size_t)N * 4;
    int* off    = (int*)p;  p += (size_t)(N + 1) * 4;
    int* bsum   = (int*)p;  p += 64 * 4;
    int* cursor = (int*)p;  p += (size_t)N * 4;
    int* col    = (int*)p;

    const int nb = (N + 1023) / 1024;

    hipMemsetAsync(deg, 0, (size_t)N * sizeof(int), stream);

    prep_hist<<<256 + (E + 255) / 256, 256, 0, stream>>>(
        W1, W2, Wq, Wk, W1f, W2f, Wqhi, Wqlo, Wkhi, Wklo, dst, deg, E);
    qk_mfma<<<(N + 31) / 32, 256, 0, stream>>>(feat, Wqhi, Wqlo, Wkhi, Wklo,
                                               kq, N);
    scan_blk<<<nb, 1024, 0, stream>>>(deg, off, bsum, N);
    scan_mid<<<1, 64, 0, stream>>>(bsum, nb);
    scan_add<<<nb, 1024, 0, stream>>>(off, cursor, bsum, N, E);
    scatter_kernel<<<(E + 255) / 256, 256, 0, stream>>>(src, dst, cursor, col, E);
    sort_csr<<<(N + 3) / 4, 256, 0, stream>>>(off, col, N);
    gather_ln1<<<(Npad + 3) / 4, 256, 0, stream>>>(feat, kq, off, col, ln_g, ln_b,
                                                   xb, xf, N, Npad);
    ffn_fused<<<(N + 31) / 32, 512, 0, stream>>>(xb, xf, W1f, W2f, b1, alpha,
                                                 b2, ln_g, ln_b, out, N);
}

// Round 14
// 235.832 us; speedup vs baseline: 1.5917x; 1.0286x over previous
//
#include <hip/hip_runtime.h>
#include <math.h>

#define NF 128
#define FH 512
#define SQRT_DH 5.656854249492380f
#define LN_EPS 1e-5f

typedef __attribute__((ext_vector_type(8))) short short8;
typedef __attribute__((ext_vector_type(4))) float f32x4;

__device__ __forceinline__ unsigned short f2bf(float x) {
    union { float f; unsigned u; } c; c.f = x;
    unsigned u = c.u;
    return (unsigned short)((u + 0x7fffu + ((u >> 16) & 1u)) >> 16);
}
__device__ __forceinline__ float bf2f(unsigned short h) {
    union { unsigned u; float f; } c; c.u = (unsigned)h << 16; return c.f;
}
__device__ __forceinline__ float lo_bf(unsigned u) {
    union { unsigned u; float f; } c; c.u = u << 16; return c.f;
}
__device__ __forceinline__ float hi_bf(unsigned u) {
    union { unsigned u; float f; } c; c.u = u & 0xffff0000u; return c.f;
}

// ---------------- weight prep ∥ dst histogram (block-specialized) -----------
__global__ __launch_bounds__(256) void prep_hist(
    const float* __restrict__ W1, const float* __restrict__ W2,
    const float* __restrict__ Wq, const float* __restrict__ Wk,
    unsigned short* __restrict__ W1f, unsigned short* __restrict__ W2f,
    unsigned short* __restrict__ Wqhi, unsigned short* __restrict__ Wqlo,
    unsigned short* __restrict__ Wkhi, unsigned short* __restrict__ Wklo,
    const int* __restrict__ dst, int* __restrict__ deg, int E)
{
    if (blockIdx.x >= 256) {
        int i = (blockIdx.x - 256) * 256 + threadIdx.x;
        if (i < E) atomicAdd(&deg[dst[i]], 1);
        return;
    }
    int f = blockIdx.x * 256 + threadIdx.x;   // 0..65535
    int i = f & 7, l = (f >> 3) & 63;
    int lg = l >> 4, l15 = l & 15;
    {
        int ntg = (f >> 9) & 31, kt = f >> 14;
        int k = kt * 32 + lg * 8 + i, n = ntg * 16 + l15;
        W1f[f] = f2bf(W1[k * FH + n]);
    }
    {
        int nt2 = (f >> 9) & 7, kt2 = f >> 12;
        int k = kt2 * 32 + lg * 8 + i, n = nt2 * 16 + l15;
        W2f[f] = f2bf(W2[k * NF + n]);
    }
    if (f < 16384) {
        int nt = (f >> 9) & 7, kt = f >> 12;
        int k = kt * 32 + lg * 8 + i, n = nt * 16 + l15;
        float vq = Wq[k * NF + n];
        unsigned short qh = f2bf(vq);
        Wqhi[f] = qh; Wqlo[f] = f2bf(vq - bf2f(qh));
        float vk = Wk[k * NF + n];
        unsigned short kh = f2bf(vk);
        Wkhi[f] = kh; Wklo[f] = f2bf(vk - bf2f(kh));
    }
}

// ---------------- q/k projections via MFMA (hi/lo split) --------------------
__global__ __launch_bounds__(256) void qk_mfma(
    const float* __restrict__ feat,
    const unsigned short* __restrict__ Wqhi, const unsigned short* __restrict__ Wqlo,
    const unsigned short* __restrict__ Wkhi, const unsigned short* __restrict__ Wklo,
    unsigned* __restrict__ kq, int N)
{
    const int tid = threadIdx.x;
    const int l = tid & 63, wid = tid >> 6;
    const int l15 = l & 15, lg = l >> 4;
    const int n0 = blockIdx.x * 32;

    f32x4 accq[2][2], acck[2][2];
    #pragma unroll
    for (int mf = 0; mf < 2; ++mf)
        #pragma unroll
        for (int nt = 0; nt < 2; ++nt) {
            accq[mf][nt] = (f32x4){0.f, 0.f, 0.f, 0.f};
            acck[mf][nt] = (f32x4){0.f, 0.f, 0.f, 0.f};
        }

    #pragma unroll
    for (int kt = 0; kt < 4; ++kt) {
        short8 ahi[2], alo[2];
        #pragma unroll
        for (int mf = 0; mf < 2; ++mf) {
            int n = n0 + mf * 16 + l15;
            float v[8];
            if (n < N) {
                const float4* p = (const float4*)(feat + (size_t)n * NF + kt * 32 + lg * 8);
                float4 v0 = p[0], v1 = p[1];
                v[0] = v0.x; v[1] = v0.y; v[2] = v0.z; v[3] = v0.w;
                v[4] = v1.x; v[5] = v1.y; v[6] = v1.z; v[7] = v1.w;
            } else {
                #pragma unroll
                for (int i = 0; i < 8; ++i) v[i] = 0.f;
            }
            #pragma unroll
            for (int i = 0; i < 8; ++i) {
                unsigned short h = f2bf(v[i]);
                ahi[mf][i] = (short)h;
                alo[mf][i] = (short)f2bf(v[i] - bf2f(h));
            }
        }
        #pragma unroll
        for (int nt = 0; nt < 2; ++nt) {
            int ntg = wid * 2 + nt;
            size_t fo = ((size_t)(kt * 8 + ntg) * 64 + l) * 8;
            short8 bqh = *(const short8*)(Wqhi + fo);
            short8 bql = *(const short8*)(Wqlo + fo);
            short8 bkh = *(const short8*)(Wkhi + fo);
            short8 bkl = *(const short8*)(Wklo + fo);
            #pragma unroll
            for (int mf = 0; mf < 2; ++mf) {
                accq[mf][nt] = __builtin_amdgcn_mfma_f32_16x16x32_bf16(ahi[mf], bqh, accq[mf][nt], 0, 0, 0);
                accq[mf][nt] = __builtin_amdgcn_mfma_f32_16x16x32_bf16(alo[mf], bqh, accq[mf][nt], 0, 0, 0);
                accq[mf][nt] = __builtin_amdgcn_mfma_f32_16x16x32_bf16(ahi[mf], bql, accq[mf][nt], 0, 0, 0);
                acck[mf][nt] = __builtin_amdgcn_mfma_f32_16x16x32_bf16(ahi[mf], bkh, acck[mf][nt], 0, 0, 0);
                acck[mf][nt] = __builtin_amdgcn_mfma_f32_16x16x32_bf16(alo[mf], bkh, acck[mf][nt], 0, 0, 0);
                acck[mf][nt] = __builtin_amdgcn_mfma_f32_16x16x32_bf16(ahi[mf], bkl, acck[mf][nt], 0, 0, 0);
            }
        }
    }

    #pragma unroll
    for (int mf = 0; mf < 2; ++mf) {
        #pragma unroll
        for (int nt = 0; nt < 2; ++nt) {
            int colg = wid * 32 + nt * 16 + l15;
            #pragma unroll
            for (int r = 0; r < 4; ++r) {
                int n = n0 + mf * 16 + lg * 4 + r;
                if (n < N) {
                    float kk = acck[mf][nt][r];
                    float qq = accq[mf][nt][r];
                    float e = __expf(SQRT_DH * kk);
                    kq[(size_t)n * NF + colg] =
                        ((unsigned)f2bf(qq * e) << 16) | (unsigned)f2bf(e);
                }
            }
        }
    }
}

// ---------------- CSR build ------------------------------------------------
__global__ __launch_bounds__(1024) void scan_blk(
    const int* __restrict__ deg, int* __restrict__ off,
    int* __restrict__ bsum, int N)
{
    __shared__ int ws[16];
    const int tid = threadIdx.x, lane = tid & 63, w = tid >> 6;
    int i = blockIdx.x * 1024 + tid;
    int v = (i < N) ? deg[i] : 0;
    int x = v;
    #pragma unroll
    for (int o = 1; o < 64; o <<= 1) {
        int t = __shfl_up(x, o);
        if (lane >= o) x += t;
    }
    if (lane == 63) ws[w] = x;
    __syncthreads();
    if (w == 0 && lane < 16) {
        int s = ws[lane];
        #pragma unroll
        for (int o = 1; o < 16; o <<= 1) {
            int t = __shfl_up(s, o);
            if (lane >= o) s += t;
        }
        ws[lane] = s;
    }
    __syncthreads();
    int wbase = (w == 0) ? 0 : ws[w - 1];
    int incl = wbase + x;
    if (i < N) off[i] = incl - v;
    if (tid == 1023) bsum[blockIdx.x] = incl;
}

// scan_add v2: folds the middle scan in (each block wave-scans bsum[0..nb),
// nb <= 64) — removes the scan_mid launch.
__global__ __launch_bounds__(1024) void scan_add(
    int* __restrict__ off, int* __restrict__ cursor,
    const int* __restrict__ bsum, int N, int E, int nb)
{
    __shared__ int base_s;
    const int tid = threadIdx.x;
    if (tid < 64) {
        int v = (tid < nb) ? bsum[tid] : 0;
        int x = v;
        #pragma unroll
        for (int o = 1; o < 64; o <<= 1) {
            int t = __shfl_up(x, o);
            if (tid >= o) x += t;
        }
        if (tid == (int)blockIdx.x) base_s = x - v;   // exclusive base
    }
    __syncthreads();
    int i = blockIdx.x * 1024 + tid;
    if (i < N) {
        int o = off[i] + base_s;
        off[i] = o; cursor[i] = o;
    }
    if (i == 0) off[N] = E;
}

__global__ __launch_bounds__(256) void scatter_kernel(
    const int* __restrict__ src, const int* __restrict__ dst,
    int* __restrict__ cursor, int* __restrict__ col, int E)
{
    int i = blockIdx.x * 256 + threadIdx.x;
    if (i < E) {
        int pos = atomicAdd(&cursor[dst[i]], 1);
        col[pos] = src[i];
    }
}

// canonicalize segment order: one wave per node, 64-lane bitonic via shfl_xor
__global__ __launch_bounds__(256) void sort_csr(
    const int* __restrict__ off, int* __restrict__ col, int N)
{
    const int wid  = threadIdx.x >> 6;
    const int lane = threadIdx.x & 63;
    const int n = blockIdx.x * 4 + wid;
    if (n >= N) return;
    const int e0 = off[n], e1 = off[n + 1];
    const int len = e1 - e0;
    if (len <= 1) return;
    if (len <= 64) {
        int v = (lane < len) ? col[e0 + lane] : 0x7fffffff;
        #pragma unroll
        for (int k = 2; k <= 64; k <<= 1) {
            #pragma unroll
            for (int j = k >> 1; j > 0; j >>= 1) {
                int other = __shfl_xor(v, j);
                bool keepMin = (((lane & j) == 0) == ((lane & k) == 0));
                v = keepMin ? (v < other ? v : other)
                            : (v > other ? v : other);
            }
        }
        if (lane < len) col[e0 + lane] = v;
    } else if (lane == 0) {
        for (int i = e0 + 1; i < e1; ++i) {
            int v = col[i];
            int j = i - 1;
            while (j >= e0 && col[j] > v) { col[j + 1] = col[j]; --j; }
            col[j + 1] = v;
        }
    }
}

// ---------------- gather + residual + LN1 (wave-per-node, col prefetch) ----
// Lane i preloads col[e0+i]; inner loop broadcasts src via __shfl with a
// wave-uniform index (-> v_readlane/SGPR base) — kq loads have no per-iter
// memory dependency. Summation ascending (col pre-sorted), 4-acc interleave.
__global__ __launch_bounds__(256) void gather_ln1(
    const float* __restrict__ feat, const unsigned* __restrict__ kq,
    const int* __restrict__ off, const int* __restrict__ col,
    const float* __restrict__ ln_g, const float* __restrict__ ln_b,
    unsigned short* __restrict__ xb, float* __restrict__ xf, int N, int Npad)
{
    const int lane = threadIdx.x & 63;
    const int wv   = threadIdx.x >> 6;
    const int n    = blockIdx.x * 4 + wv;
    if (n >= Npad) return;
    const int c0 = lane * 2;

    const float g0 = ln_g[c0], g1 = ln_g[c0 + 1];
    const float bb0 = ln_b[c0], bb1 = ln_b[c0 + 1];

    float x0 = 0.f, x1 = 0.f;
    const bool valid = (n < N);
    if (valid) {
        const int e0 = off[n], e1 = off[n + 1];
        const int len = e1 - e0;
        if (len > 0) {
            const int lenc = len < 64 ? len : 64;
            int cv = col[e0 + (lane < lenc ? lane : 0)];
            float dA0 = 0.f, qA0 = 0.f, dA1 = 0.f, qA1 = 0.f;
            float dB0 = 0.f, qB0 = 0.f, dB1 = 0.f, qB1 = 0.f;
            float dC0 = 0.f, qC0 = 0.f, dC1 = 0.f, qC1 = 0.f;
            float dD0 = 0.f, qD0 = 0.f, dD1 = 0.f, qD1 = 0.f;
            int e = 0;
            for (; e + 3 < lenc; e += 4) {
                int sA = __shfl(cv, e);
                int sB = __shfl(cv, e + 1);
                int sC = __shfl(cv, e + 2);
                int sD = __shfl(cv, e + 3);
                uint2 uA = *(const uint2*)(kq + (size_t)sA * NF + c0);
                uint2 uB = *(const uint2*)(kq + (size_t)sB * NF + c0);
                uint2 uC = *(const uint2*)(kq + (size_t)sC * NF + c0);
                uint2 uD = *(const uint2*)(kq + (size_t)sD * NF + c0);
                dA0 += lo_bf(uA.x); qA0 += hi_bf(uA.x); dA1 += lo_bf(uA.y); qA1 += hi_bf(uA.y);
                dB0 += lo_bf(uB.x); qB0 += hi_bf(uB.x); dB1 += lo_bf(uB.y); qB1 += hi_bf(uB.y);
                dC0 += lo_bf(uC.x); qC0 += hi_bf(uC.x); dC1 += lo_bf(uC.y); qC1 += hi_bf(uC.y);
                dD0 += lo_bf(uD.x); qD0 += hi_bf(uD.x); dD1 += lo_bf(uD.y); qD1 += hi_bf(uD.y);
            }
            for (; e < lenc; ++e) {
                int s = __shfl(cv, e);
                uint2 u = *(const uint2*)(kq + (size_t)s * NF + c0);
                dA0 += lo_bf(u.x); qA0 += hi_bf(u.x); dA1 += lo_bf(u.y); qA1 += hi_bf(u.y);
            }
            // rare tail (deg > 64): direct loads, memory order (pre-sorted)
            for (int ee = e0 + 64; ee < e1; ++ee) {
                uint2 u = *(const uint2*)(kq + (size_t)col[ee] * NF + c0);
                dA0 += lo_bf(u.x); qA0 += hi_bf(u.x); dA1 += lo_bf(u.y); qA1 += hi_bf(u.y);
            }
            dA0 += dB0 + dC0 + dD0; qA0 += qB0 + qC0 + qD0;
            dA1 += dB1 + dC1 + dD1; qA1 += qB1 + qC1 + qD1;
            x0 = qA0 / dA0; x1 = qA1 / dA1;
        }
        const float2 fv = *(const float2*)(feat + (size_t)n * NF + c0);
        x0 += fv.x; x1 += fv.y;
    }
    float S = x0 + x1, Q = x0 * x0 + x1 * x1;
    #pragma unroll
    for (int o = 1; o < 64; o <<= 1) {
        S += __shfl_xor(S, o);
        Q += __shfl_xor(Q, o);
    }
    float mean = S * (1.f / NF);
    float msq  = Q * (1.f / NF);
    float rs   = rsqrtf(msq - mean * mean + LN_EPS);
    float v0 = valid ? ((x0 - mean) * rs * g0 + bb0) : 0.f;
    float v1 = valid ? ((x1 - mean) * rs * g1 + bb1) : 0.f;
    *(unsigned*)(xb + (size_t)n * NF + c0) =
        (unsigned)f2bf(v0) | ((unsigned)f2bf(v1) << 16);
    *(float2*)(xf + (size_t)n * NF + c0) = make_float2(v0, v1);
}

// ---------------- fused FFN v7: BM=32, 8 waves -----------------------------
__global__ __launch_bounds__(512) void ffn_fused(
    const unsigned short* __restrict__ xb, const float* __restrict__ xf,
    const unsigned short* __restrict__ W1f, const unsigned short* __restrict__ W2f,
    const float* __restrict__ b1, const float* __restrict__ alpha,
    const float* __restrict__ b2,
    const float* __restrict__ ln_g, const float* __restrict__ ln_b,
    float* __restrict__ out, int N)
{
    __shared__ unsigned short hlds[32 * 512];   // 32 KB, swizzled
    __shared__ float sredS[32][8];
    __shared__ float sredQ[32][8];

    const int tid = threadIdx.x;
    const int l = tid & 63;
    const int wid = tid >> 6;          // 0..7
    const int l15 = l & 15;
    const int lg = l >> 4;
    const int n0 = blockIdx.x * 32;

    char* hbase = (char*)hlds;

    f32x4 acc[2][4];
    #pragma unroll
    for (int mf = 0; mf < 2; ++mf)
        #pragma unroll
        for (int nt = 0; nt < 4; ++nt)
            acc[mf][nt] = (f32x4){0.f, 0.f, 0.f, 0.f};

    #pragma unroll
    for (int kt = 0; kt < 4; ++kt) {
        short8 a0 = *(const short8*)(xb + (size_t)(n0 + l15)      * NF + kt * 32 + lg * 8);
        short8 a1 = *(const short8*)(xb + (size_t)(n0 + 16 + l15) * NF + kt * 32 + lg * 8);
        #pragma unroll
        for (int nt = 0; nt < 4; ++nt) {
            short8 b = *(const short8*)(W1f + ((kt * 32 + wid * 4 + nt) * 64 + l) * 8);
            acc[0][nt] = __builtin_amdgcn_mfma_f32_16x16x32_bf16(a0, b, acc[0][nt], 0, 0, 0);
            acc[1][nt] = __builtin_amdgcn_mfma_f32_16x16x32_bf16(a1, b, acc[1][nt], 0, 0, 0);
        }
    }

    #pragma unroll
    for (int nt = 0; nt < 4; ++nt) {
        int j = wid * 64 + nt * 16 + l15;    // 0..511
        float b1j = b1[j], alj = alpha[j];
        #pragma unroll
        for (int mf = 0; mf < 2; ++mf) {
            #pragma unroll
            for (int r = 0; r < 4; ++r) {
                int row = mf * 16 + lg * 4 + r;
                float hv = acc[mf][nt][r] + b1j;
                hv = hv > 0.f ? hv : alj * hv;
                int byte = row * 1024 + ((j * 2) ^ ((row & 7) << 4));
                *(unsigned short*)(hbase + byte) = f2bf(hv);
            }
        }
    }
    __syncthreads();

    const int c0 = wid * 16 + l15;
    const float b20 = b2[c0];
    const float gg0 = ln_g[c0];
    const float bb0 = ln_b[c0];
    float xv[2][4];
    #pragma unroll
    for (int mf = 0; mf < 2; ++mf)
        #pragma unroll
        for (int r = 0; r < 4; ++r) {
            size_t n = (size_t)(n0 + mf * 16 + lg * 4 + r);
            xv[mf][r] = xf[n * NF + c0];
        }

    f32x4 acc2[2];
    acc2[0] = (f32x4){0.f, 0.f, 0.f, 0.f};
    acc2[1] = (f32x4){0.f, 0.f, 0.f, 0.f};

    #pragma unroll
    for (int kt = 0; kt < 16; ++kt) {
        int jb = kt * 64 + lg * 16;
        int row0 = l15, row1 = 16 + l15;
        short8 a0 = *(const short8*)(hbase + row0 * 1024 + (jb ^ ((row0 & 7) << 4)));
        short8 a1 = *(const short8*)(hbase + row1 * 1024 + (jb ^ ((row1 & 7) << 4)));
        short8 b = *(const short8*)(W2f + ((kt * 8 + wid) * 64 + l) * 8);
        acc2[0] = __builtin_amdgcn_mfma_f32_16x16x32_bf16(a0, b, acc2[0], 0, 0, 0);
        acc2[1] = __builtin_amdgcn_mfma_f32_16x16x32_bf16(a1, b, acc2[1], 0, 0, 0);
    }

    float y[2][4];
    #pragma unroll
    for (int mf = 0; mf < 2; ++mf) {
        #pragma unroll
        for (int r = 0; r < 4; ++r) {
            int row = mf * 16 + lg * 4 + r;
            float a = acc2[mf][r] + b20 + xv[mf][r];
            y[mf][r] = a;
            float p1 = a, p2 = a * a;
            #pragma unroll
            for (int o = 1; o < 16; o <<= 1) {
                p1 += __shfl_xor(p1, o);
                p2 += __shfl_xor(p2, o);
            }
            if (l15 == 0) { sredS[row][wid] = p1; sredQ[row][wid] = p2; }
        }
    }
    __syncthreads();

    #pragma unroll
    for (int mf = 0; mf < 2; ++mf) {
        #pragma unroll
        for (int r = 0; r < 4; ++r) {
            int row = mf * 16 + lg * 4 + r;
            int n = n0 + row;
            float S = 0.f, Q = 0.f;
            #pragma unroll
            for (int w = 0; w < 8; ++w) { S += sredS[row][w]; Q += sredQ[row][w]; }
            float mean = S * (1.f / NF);
            float msq  = Q * (1.f / NF);
            float rs   = rsqrtf(msq - mean * mean + LN_EPS);
            if (n < N)
                out[(size_t)n * NF + c0] = (y[mf][r] - mean) * rs * gg0 + bb0;
        }
    }
}

// ---------------------------------------------------------------------------
extern "C" void kernel_launch(void* const* d_in, const int* in_sizes, int n_in,
                              void* d_out, int out_size, void* d_ws, size_t ws_size,
                              hipStream_t stream)
{
    const float* feat  = (const float*)d_in[0];
    const float* Wq    = (const float*)d_in[1];
    const float* Wk    = (const float*)d_in[2];
    // d_in[3] = Wv — cancels in per-channel edge softmax, unused.
    const float* ln_g  = (const float*)d_in[4];
    const float* ln_b  = (const float*)d_in[5];
    const float* W1    = (const float*)d_in[6];
    const float* b1    = (const float*)d_in[7];
    const float* alpha = (const float*)d_in[8];
    const float* W2    = (const float*)d_in[9];
    const float* b2    = (const float*)d_in[10];
    const int*   src   = (const int*)d_in[11];
    const int*   dst   = (const int*)d_in[12];

    const int N = in_sizes[0] / NF;
    const int E = in_sizes[11];
    const int Npad = ((N + 63) / 64) * 64;
    float* out = (float*)d_out;

    char* p = (char*)d_ws;
    unsigned*       kq  = (unsigned*)p;       p += (size_t)N * NF * 4;
    unsigned short* xb  = (unsigned short*)p; p += (size_t)Npad * NF * 2;
    float*          xf  = (float*)p;          p += (size_t)Npad * NF * 4;
    unsigned short* W1f = (unsigned short*)p; p += (size_t)NF * FH * 2;
    unsigned short* W2f = (unsigned short*)p; p += (size_t)FH * NF * 2;
    unsigned short* Wqhi = (unsigned short*)p; p += (size_t)NF * NF * 2;
    unsigned short* Wqlo = (unsigned short*)p; p += (size_t)NF * NF * 2;
    unsigned short* Wkhi = (unsigned short*)p; p += (size_t)NF * NF * 2;
    unsigned short* Wklo = (unsigned short*)p; p += (size_t)NF * NF * 2;
    int* deg    = (int*)p;  p += (size_t)N * 4;
    int* off    = (int*)p;  p += (size_t)(N + 1) * 4;
    int* bsum   = (int*)p;  p += 64 * 4;
    int* cursor = (int*)p;  p += (size_t)N * 4;
    int* col    = (int*)p;

    const int nb = (N + 1023) / 1024;

    hipMemsetAsync(deg, 0, (size_t)N * sizeof(int), stream);

    prep_hist<<<256 + (E + 255) / 256, 256, 0, stream>>>(
        W1, W2, Wq, Wk, W1f, W2f, Wqhi, Wqlo, Wkhi, Wklo, dst, deg, E);
    qk_mfma<<<(N + 31) / 32, 256, 0, stream>>>(feat, Wqhi, Wqlo, Wkhi, Wklo,
                                               kq, N);
    scan_blk<<<nb, 1024, 0, stream>>>(deg, off, bsum, N);
    scan_add<<<nb, 1024, 0, stream>>>(off, cursor, bsum, N, E, nb);
    scatter_kernel<<<(E + 255) / 256, 256, 0, stream>>>(src, dst, cursor, col, E);
    sort_csr<<<(N + 3) / 4, 256, 0, stream>>>(off, col, N);
    gather_ln1<<<(Npad + 3) / 4, 256, 0, stream>>>(feat, kq, off, col, ln_g, ln_b,
                                                   xb, xf, N, Npad);
    ffn_fused<<<(N + 31) / 32, 512, 0, stream>>>(xb, xf, W1f, W2f, b1, alpha,
                                                 b2, ln_g, ln_b, out, N);
}